// Round 6
// baseline (289.667 us; speedup 1.0000x reference)
//
#include <hip/hip_runtime.h>
#include <math.h>

// CapsuleLayer dynamic routing, MI355X.
// B=4096, L=200, Din=Dout=64, K=8, 3 iterations.
//
// Key identity: low_new = lc @ S never needs materializing.
//   high_pre = W @ (lc@S) = (W@lc) @ S             (hp then tiny projection)
//   delta    = high @ (lc@S)^T = (high@S^T) @ lc^T (hs then row dots)
// Only big array touched is lc (210 MB, fits 256 MB L3).
//
// R5 -> R6: step 2 rewritten branch-free float2-per-lane (1 dwordx2 + 8
// broadcast ds_read_b32 + 16 FMA per iter, 16 indep FMA chains); R5 counters
// showed duration invariant to HBM-vs-L3 source => issue/latency-bound, so
// the lever is load-instr count + cross-iteration pipelining, not BW.
//
// ws layout (floats): Bc[1600] | St[4096] | partial[B*K*L = 6,553,600]
// partial2 [16*K*L] lives in d_out (fully overwritten by the final pass).

#define B_SZ  4096
#define L_SZ  200
#define DINK  64
#define DOUTK 64
#define K_SZ  8

// ---------------------------- init: copy Bc + transpose S into St
__global__ __launch_bounds__(256) void k_init(const float* __restrict__ Bm,
                                              const float* __restrict__ S,
                                              float* __restrict__ Bc,
                                              float* __restrict__ St) {
    int i = blockIdx.x * 256 + threadIdx.x;
    if (i < K_SZ * L_SZ) Bc[i] = Bm[i];
    int j = i - K_SZ * L_SZ;
    if (j >= 0 && j < DINK * DOUTK) {
        int o = j >> 6, ii = j & 63;
        St[j] = S[ii * DOUTK + o];     // St[o][i] = S[i][o]
    }
}

// ------------------------------------------- one routing iteration (fused)
// grid 4096 (one block per batch) x 256 threads.
// WRITE_OUT=0: compute delta partial. WRITE_OUT=1: write final high.
template<int WRITE_OUT>
__global__ __launch_bounds__(256) void k_route(const float* __restrict__ lc_g,
                                               const int* __restrict__ seq_len,
                                               const float* __restrict__ S_g,
                                               const float* __restrict__ St_g,
                                               const float* __restrict__ Bc,
                                               float* __restrict__ partial,
                                               float* __restrict__ out) {
    __shared__ float W_s[K_SZ][L_SZ];      // 6.4 KB  unnormalized exp(B-m)
    __shared__ float hp_s[K_SZ][DINK];     // 2 KB    W@lc normalized
    __shared__ float ovl[4 * K_SZ * DINK]; // 8 KB:  phase A hp_part[4][8][64]
                                           //        phase B hx[8][64] | hs[8][64]
    float (*hp_part)[K_SZ][DINK] = (float (*)[K_SZ][DINK])ovl;
    float (*hx_s)[DINK] = (float (*)[DINK])(ovl);
    float (*hs_s)[DINK] = (float (*)[DINK])(ovl + K_SZ * DINK);

    int t = threadIdx.x;
    int b = blockIdx.x;
    long lbase = (long)b * (L_SZ * DINK);
    const float* lcb = lc_g + lbase;
    const float2* lc2 = (const float2*)lcb;
    int sl = seq_len[b];
    int k = t >> 5, g = t & 31;            // group mapping (softmax & tiny mats)
    int w = t >> 6;                        // wave index
    int sub = (t >> 5) & 1;                // sub-row within wave (lane>>5)
    int p = t & 31;                        // column-pair within sub-group

    // 1. masked softmax stats over L for row k (32 lanes per k)
    const float* bk = Bc + k * L_SZ;
    float m = -3.4e38f;
    for (int l = g; l < sl; l += 32) m = fmaxf(m, bk[l]);
    #pragma unroll
    for (int s = 16; s; s >>= 1) m = fmaxf(m, __shfl_xor(m, s, 32));
    float sum = 0.f;
    for (int l = g; l < sl; l += 32) {
        float e = __expf(bk[l] - m);
        sum += e;
        W_s[k][l] = e;                      // normalization folded into step 3
    }
    #pragma unroll
    for (int s = 16; s; s >>= 1) sum += __shfl_xor(sum, s, 32);
    float rinv = 1.0f / sum;                // thread (k,g) reuses this in step 3
    __syncthreads();                        // B1

    // 2. branch-free wave-chunk hp partials.
    //    Wave w, sub-row sub owns rows l = 8j + 2w + sub; lane covers cols 2p,2p+1.
    //    Per iter: 1 dwordx2 + 8 broadcast ds_read_b32 + 16 FMA (indep chains).
    {
        float2 acc[K_SZ];
        #pragma unroll
        for (int kk = 0; kk < K_SZ; ++kk) acc[kk] = make_float2(0.f, 0.f);
        int l0 = 2 * w + sub;
        int n = (sl - l0 + 7) >> 3;         // trip count; <=0 -> skip
        const float2* src = lc2 + l0 * 32 + p;
        for (int j = 0; j < n; ++j) {
            float2 v = src[j * 256];        // row l0+8j, cols 2p..2p+1
            int l = l0 + 8 * j;
            #pragma unroll
            for (int kk = 0; kk < K_SZ; ++kk) {
                float wv = W_s[kk][l];      // 2 addrs/wave broadcast
                acc[kk].x += wv * v.x; acc[kk].y += wv * v.y;
            }
        }
        // fold the two sub-rows (lane ^ 32 holds same cols, other row set)
        #pragma unroll
        for (int kk = 0; kk < K_SZ; ++kk) {
            acc[kk].x += __shfl_xor(acc[kk].x, 32, 64);
            acc[kk].y += __shfl_xor(acc[kk].y, 32, 64);
        }
        if (sub == 0) {
            #pragma unroll
            for (int kk = 0; kk < K_SZ; ++kk)
                *(float2*)&hp_part[w][kk][2 * p] = acc[kk];
        }
    }
    __syncthreads();                        // B2

    // 3. reduce hp over the 4 wave-chunks; fold in rinv
    {
        float2 r = make_float2(0.f, 0.f);
        #pragma unroll
        for (int cc = 0; cc < 4; ++cc) {
            float2 q = *(const float2*)&hp_part[cc][k][2 * g];
            r.x += q.x; r.y += q.y;
        }
        *(float2*)&hp_s[k][2 * g] = make_float2(r.x * rinv, r.y * rinv);
    }
    __syncthreads();                        // B3 (also overlay anti-hazard)

    // 4. high[k][o] = sum_i hp[k][i]*S[i][o]; squash. o=2g,2g+1; S coalesced.
    {
        float h0 = 0.f, h1 = 0.f;
        const float* sp = S_g + 2 * g;
        #pragma unroll 8
        for (int i = 0; i < DINK; ++i) {
            float pv = hp_s[k][i];                        // LDS broadcast
            float2 sv = *(const float2*)(sp + i * DOUTK); // L1-hot, coalesced
            h0 += pv * sv.x; h1 += pv * sv.y;
        }
        float nn = h0 * h0 + h1 * h1;
        #pragma unroll
        for (int s = 16; s; s >>= 1) nn += __shfl_xor(nn, s, 32);
        float sc = nn / ((1.0f + nn) * sqrtf(nn + 1e-9f));
        h0 *= sc; h1 *= sc;
        if (WRITE_OUT) {
            float2* ob2 = (float2*)(out + (long)b * (K_SZ * DOUTK) + k * DOUTK);
            ob2[g] = make_float2(h0, h1);
            return;
        }
        *(float2*)&hx_s[k][2 * g] = make_float2(h0, h1);
        // consumer of hx_s[k][*] is this same wave -> no barrier needed
    }

    // 5. hs[k][i] = sum_o high[k][o]*S[i][o] via St (transposed): coalesced.
    {
        float s0 = 0.f, s1 = 0.f;
        const float* stp = St_g + 2 * g;
        #pragma unroll 8
        for (int o = 0; o < DOUTK; ++o) {
            float hv = hx_s[k][o];                        // LDS broadcast, same wave
            float2 sv = *(const float2*)(stp + o * DINK); // L1-hot, coalesced
            s0 += hv * sv.x; s1 += hv * sv.y;
        }
        *(float2*)&hs_s[k][2 * g] = make_float2(s0, s1);
    }
    __syncthreads();                        // B4: hs read cross-wave below

    // 6. delta partial[k][l] = sum_i hs[k][i]*lc[l][i]  (ALL l, unmasked)
    if (t < L_SZ) {
        const float4* row4 = (const float4*)(lcb + (long)t * DINK);
        float* pb = partial + (long)b * (K_SZ * L_SZ);
        float acc[K_SZ] = {};
        #pragma unroll
        for (int i4 = 0; i4 < 16; ++i4) {
            float4 v = row4[i4];            // L1/L2-hot from step 2
            #pragma unroll
            for (int kk = 0; kk < K_SZ; ++kk) {
                float4 h = *(const float4*)&hs_s[kk][i4 * 4];  // b128 broadcast
                acc[kk] += v.x * h.x + v.y * h.y + v.z * h.z + v.w * h.w;
            }
        }
        #pragma unroll
        for (int kk = 0; kk < K_SZ; ++kk)
            pb[kk * L_SZ + t] = acc[kk];    // coalesced over t
    }
}

// --------------------------- deterministic two-stage reduce of partials
// Stage A: grid 800 = 50 col-groups x 16 batch-chunks; coalesced 128B reads.
__global__ __launch_bounds__(256) void k_reduceA(const float* __restrict__ partial,
                                                 float* __restrict__ partial2) {
    __shared__ float red[256];
    int x = blockIdx.x % 50;       // 32-output group
    int y = blockIdx.x / 50;       // 256-batch chunk
    int t = threadIdx.x;
    int i = x * 32 + (t & 31);
    int sub = t >> 5;
    float s = 0.f;
    for (int p = y * 256 + sub; p < (y + 1) * 256; p += 8)
        s += partial[(long)p * (K_SZ * L_SZ) + i];
    red[t] = s;
    __syncthreads();
    for (int step = 4; step >= 1; step >>= 1) {
        if (sub < step) red[t] += red[t + step * 32];
        __syncthreads();
    }
    if (sub == 0) partial2[y * (K_SZ * L_SZ) + i] = red[t];
}

// Stage B: fold 16 chunk-partials into Bc. grid 7 x 256.
__global__ __launch_bounds__(256) void k_reduceB(const float* __restrict__ partial2,
                                                 float* __restrict__ Bc) {
    int i = blockIdx.x * 256 + threadIdx.x;
    if (i < K_SZ * L_SZ) {
        float s = 0.f;
        #pragma unroll
        for (int y = 0; y < 16; ++y) s += partial2[y * (K_SZ * L_SZ) + i];
        Bc[i] += s;
    }
}

extern "C" void kernel_launch(void* const* d_in, const int* in_sizes, int n_in,
                              void* d_out, int out_size, void* d_ws, size_t ws_size,
                              hipStream_t stream) {
    const float* lc = (const float*)d_in[0];   // [4096,200,64]
    const int*   sl = (const int*)d_in[1];     // [4096,1]
    const float* Bm = (const float*)d_in[2];   // [1,8,200]
    const float* S  = (const float*)d_in[3];   // [64,64]
    float* out = (float*)d_out;                // [4096,8,64]
    float* ws  = (float*)d_ws;

    float* Bc      = ws;                       // 1,600 floats
    float* St      = ws + 1600;                // 4,096 floats (S transposed)
    float* partial = St + 4096;                // 6,553,600 floats
    float* p2      = out;                      // scratch: overwritten by final pass

    k_init<<<23, 256, 0, stream>>>(Bm, S, Bc, St);

    k_route<0><<<B_SZ, 256, 0, stream>>>(lc, sl, S, St, Bc, partial, out);
    k_reduceA <<<800, 256, 0, stream>>>(partial, p2);
    k_reduceB <<<7, 256, 0, stream>>>(p2, Bc);
    k_route<0><<<B_SZ, 256, 0, stream>>>(lc, sl, S, St, Bc, partial, out);
    k_reduceA <<<800, 256, 0, stream>>>(partial, p2);
    k_reduceB <<<7, 256, 0, stream>>>(p2, Bc);
    k_route<1><<<B_SZ, 256, 0, stream>>>(lc, sl, S, St, Bc, partial, out);
}